// Round 15
// baseline (127.678 us; speedup 1.0000x reference)
//
#include <hip/hip_runtime.h>
#include <math.h>

// PHOSA interaction loss, MI355X — round 15: r14 (62.1 us) + SORTED part
// index lists. The lists are batch-independent: one 16-block bitonic sort
// (deterministic, LDS-resident, ~4 us) makes every gather walk its window
// monotonically, and the r13 position-splits become contiguous VALUE ranges
// -> all parts' quarter-h blocks touch the same ~196 KB region (amplifies
// the r12 locality mechanism that gave FETCH 185->150 MB).
// Correctness: same multiset -> min/max EXACT (mask bits identical); part
// sums reorder (~1e-8 vs 3.16e-5 threshold); loss_inter path bitwise same.
constexpr int B_   = 256;
constexpr int NS_  = 10475;
constexpr int NO_  = 65536;
constexpr int P_   = 8;
constexpr int KS_  = 1024;
constexpr int KO_  = 2048;
constexpr int NBLK_S = 4;    // stream blocks per batch, smpl
constexpr int NBLK_O = 16;   // stream blocks per batch, object (4096 verts)
constexpr int DIVO_ = 4;     // obj gather split
constexpr int DIVS_ = 2;     // smpl gather split
constexpr float EPS_ = 1e-9f;
constexpr float ZTH_ = 5.0f;

// per-batch units: 16 objsum | 32 objgather-qtr | 4 smplsum | 16 smplgather-half
constexpr int GO_ = P_ * DIVO_;                          // 32
constexpr int GS_ = P_ * DIVS_;                          // 16
constexpr int UNITS_PER_B = NBLK_O + GO_ + NBLK_S + GS_; // 68
constexpr int NXCD = 8;
constexpr int NSLOT = B_ / NXCD;                         // 32

// 16 B vector with 4 B alignment (emits global_load_dwordx4 from 12 B stride).
typedef float f32x4a4 __attribute__((ext_vector_type(4), aligned(4)));

#define DEV_INLINE __device__ __forceinline__

DEV_INLINE float wredsum(float v) {
#pragma unroll
    for (int o = 32; o; o >>= 1) v += __shfl_down(v, o);
    return v;
}
DEV_INLINE float wredmin(float v) {
#pragma unroll
    for (int o = 32; o; o >>= 1) v = fminf(v, __shfl_down(v, o));
    return v;
}
DEV_INLINE float wredmax(float v) {
#pragma unroll
    for (int o = 32; o; o >>= 1) v = fmaxf(v, __shfl_down(v, o));
    return v;
}

// ---------------------------------------------------------------------------
// Kernel 0: bitonic sort of each part's index list (blocks 0-7: obj parts,
// 8-15: smpl parts). LDS-resident, deterministic. Duplicates preserved.
// ---------------------------------------------------------------------------
__global__ __launch_bounds__(256) void sort_idx_kernel(
        const int* __restrict__ oidx, const int* __restrict__ sidx,
        int* __restrict__ sortedO, int* __restrict__ sortedS) {
    __shared__ int s[KO_];
    const int t = threadIdx.x;
    const bool isObj = blockIdx.x < P_;
    const int p = isObj ? blockIdx.x : blockIdx.x - P_;
    const int K = isObj ? KO_ : KS_;
    const int* src = isObj ? (oidx + (size_t)p * KO_) : (sidx + (size_t)p * KS_);
    int* dst = isObj ? (sortedO + (size_t)p * KO_) : (sortedS + (size_t)p * KS_);
    for (int i = t; i < K; i += 256) s[i] = src[i];
    __syncthreads();
    for (int k = 2; k <= K; k <<= 1) {
        for (int j = k >> 1; j > 0; j >>= 1) {
            for (int i = t; i < K; i += 256) {
                const int ixj = i ^ j;
                if (ixj > i) {
                    const int a = s[i], b = s[ixj];
                    const bool up = ((i & k) == 0);
                    if (up ? (a > b) : (a < b)) { s[i] = b; s[ixj] = a; }
                }
            }
            __syncthreads();
        }
    }
    for (int i = t; i < K; i += 256) dst[i] = s[i];
}

// ---------------------------------------------------------------------------
// Object stream role: float4-vectorized batch partial sums (verbatim r9/r14).
// ---------------------------------------------------------------------------
DEV_INLINE void batch_sum_obj_body(const float* __restrict__ v, int b, int blk,
                                   float* __restrict__ out) {
    const float4* base = reinterpret_cast<const float4*>(
        v + (size_t)b * NO_ * 3 + (size_t)blk * 4096 * 3);
    const int t = threadIdx.x;
    float4 f[12];
#pragma unroll
    for (int j = 0; j < 4; ++j) {
        const int g = j * 256 + t;
#pragma unroll
        for (int q = 0; q < 3; ++q) f[j * 3 + q] = base[g * 3 + q];
    }
    float sx = 0.f, sy = 0.f, sz = 0.f;
#pragma unroll
    for (int j = 0; j < 4; ++j) {
        const float4 f0 = f[j * 3 + 0], f1 = f[j * 3 + 1], f2 = f[j * 3 + 2];
        sx += f0.x + f0.w + f1.z + f2.y;
        sy += f0.y + f1.x + f1.w + f2.z;
        sz += f0.z + f1.y + f2.x + f2.w;
    }
    __shared__ float red[3][4];
    const float r0 = wredsum(sx), r1 = wredsum(sy), r2 = wredsum(sz);
    const int lane = t & 63, wv = t >> 6;
    if (lane == 0) { red[0][wv] = r0; red[1][wv] = r1; red[2][wv] = r2; }
    __syncthreads();
    if (t == 0) {
        float* o = out + ((size_t)b * NBLK_O + blk) * 3;
        o[0] = red[0][0] + red[0][1] + red[0][2] + red[0][3];
        o[1] = red[1][0] + red[1][1] + red[1][2] + red[1][3];
        o[2] = red[2][0] + red[2][1] + red[2][2] + red[2][3];
    }
}

// ---------------------------------------------------------------------------
// smpl stream role: scalar partial sums (verbatim round-6/8/12/13/14).
// ---------------------------------------------------------------------------
DEV_INLINE void batch_sum_smpl_body(const float* __restrict__ v, int b, int blk,
                                    float* __restrict__ out) {
    constexpr int chunk = (NS_ + NBLK_S - 1) / NBLK_S;
    const int s = blk * chunk;
    const int e = min(NS_, s + chunk);
    const float* base = v + (size_t)b * NS_ * 3;
    float sx = 0.f, sy = 0.f, sz = 0.f;
    for (int i = s + (int)threadIdx.x; i < e; i += 256) {
        const float* p = base + (size_t)i * 3;
        sx += p[0];
        sy += p[1];
        sz += p[2];
    }
    __shared__ float red[3][4];
    float r0 = wredsum(sx), r1 = wredsum(sy), r2 = wredsum(sz);
    const int lane = threadIdx.x & 63, wv = threadIdx.x >> 6;
    if (lane == 0) { red[0][wv] = r0; red[1][wv] = r1; red[2][wv] = r2; }
    __syncthreads();
    if (threadIdx.x == 0) {
        float* o = out + ((size_t)b * NBLK_S + blk) * 3;
        o[0] = red[0][0] + red[0][1] + red[0][2] + red[0][3];
        o[1] = red[1][0] + red[1][1] + red[1][2] + red[1][3];
        o[2] = red[2][0] + red[2][1] + red[2][2] + red[2][3];
    }
}

// ---------------------------------------------------------------------------
// Gather role: 1/DIV of one (batch,part) SORTED index list -> 9 split-stats.
// Position-split of a sorted list = contiguous value range -> monotone walk.
// dwordx4 per vertex; global-last vertex shifted (r10).
// ---------------------------------------------------------------------------
template <int N, int K, int DIV>
DEV_INLINE void part_stats_split_body(const float* __restrict__ v,
                                      const int* __restrict__ pidx,
                                      const float* __restrict__ Ks,
                                      int b, int p, int h,
                                      float* __restrict__ out) {
    const float fx = Ks[b * 9 + 0];
    const float cx = Ks[b * 9 + 2];
    const float fy = Ks[b * 9 + 4];
    const float cy = Ks[b * 9 + 5];
    const float* base = v + (size_t)b * N * 3;
    const int* idx = pidx + (size_t)p * K + (size_t)h * (K / DIV);
    const bool lastBatch = (b == B_ - 1);

    constexpr int ITER = (K / DIV) / 256;
    int ids[ITER];
#pragma unroll
    for (int j = 0; j < ITER; ++j) ids[j] = idx[threadIdx.x + j * 256];

    float vx[ITER], vy[ITER], vz[ITER];
#pragma unroll
    for (int j = 0; j < ITER; ++j) {
        const bool shift = lastBatch && (ids[j] == N - 1);
        const float* vp = base + (size_t)ids[j] * 3 - (shift ? 1 : 0);
        const f32x4a4 f = *reinterpret_cast<const f32x4a4*>(vp);
        vx[j] = shift ? f.y : f.x;
        vy[j] = shift ? f.z : f.y;
        vz[j] = shift ? f.w : f.z;
    }

    float umin = INFINITY, umax = -INFINITY, wmin = INFINITY, wmax = -INFINITY;
    float zmin = INFINITY, zmax = -INFINITY;
    float sx = 0.f, sy = 0.f, sz = 0.f;
#pragma unroll
    for (int j = 0; j < ITER; ++j) {
        const float x = vx[j], y = vy[j], z = vz[j];
        sx += x; sy += y; sz += z;
        zmin = fminf(zmin, z); zmax = fmaxf(zmax, z);
        float u, w;
        {
#pragma clang fp contract(off)
            const float zd = z + EPS_;
            const float x_ = x / zd;
            const float y_ = (-y) / zd;
            u = fx * x_ + cx;
            w = 1.0f - (fy * y_ + cy);
            u = 2.0f * (u - 0.5f);
            w = 2.0f * (w - 0.5f);
        }
        umin = fminf(umin, u); umax = fmaxf(umax, u);
        wmin = fminf(wmin, w); wmax = fmaxf(wmax, w);
    }

    __shared__ float red[4][9];
    float r[9];
    r[0] = wredmin(umin); r[1] = wredmax(umax);
    r[2] = wredmin(wmin); r[3] = wredmax(wmax);
    r[4] = wredmin(zmin); r[5] = wredmax(zmax);
    r[6] = wredsum(sx);   r[7] = wredsum(sy); r[8] = wredsum(sz);
    const int lane = threadIdx.x & 63, wv = threadIdx.x >> 6;
    if (lane == 0) {
#pragma unroll
        for (int q = 0; q < 9; ++q) red[wv][q] = r[q];
    }
    __syncthreads();
    if (threadIdx.x == 0) {
        float* o = out + (((size_t)b * P_ + p) * DIV + h) * 9;
        o[0] = fminf(fminf(red[0][0], red[1][0]), fminf(red[2][0], red[3][0]));
        o[1] = fmaxf(fmaxf(red[0][1], red[1][1]), fmaxf(red[2][1], red[3][1]));
        o[2] = fminf(fminf(red[0][2], red[1][2]), fminf(red[2][2], red[3][2]));
        o[3] = fmaxf(fmaxf(red[0][3], red[1][3]), fmaxf(red[2][3], red[3][3]));
        o[4] = fminf(fminf(red[0][4], red[1][4]), fminf(red[2][4], red[3][4]));
        o[5] = fmaxf(fmaxf(red[0][5], red[1][5]), fmaxf(red[2][5], red[3][5]));
        o[6] = red[0][6] + red[1][6] + red[2][6] + red[3][6];
        o[7] = red[0][7] + red[1][7] + red[2][7] + red[3][7];
        o[8] = red[0][8] + red[1][8] + red[2][8] + red[3][8];
    }
}

// ---------------------------------------------------------------------------
// Phase 1: gid -> xcd = gid&7, unit = gid>>3, slot = unit/68, role = unit%68.
// Stream roles: batch slot*8+xcd. Gather roles: previous slot's batch.
// role: [0,16) objsum | [16,48) objgather-qtr (p=r>>2, h=r&3)
//     | [48,52) smplsum | [52,68) smplgather-half (p=r>>1, h=r&1).
// ---------------------------------------------------------------------------
__global__ __launch_bounds__(256) void phase1_kernel(
        const float* __restrict__ obj, const float* __restrict__ smpl,
        const float* __restrict__ Ks,
        const int* __restrict__ sortedS, const int* __restrict__ sortedO,
        float* __restrict__ sumO, float* __restrict__ sumS,
        float* __restrict__ splitO, float* __restrict__ splitS) {
    const int gid = blockIdx.x;
    const int xcd = gid & (NXCD - 1);
    const int unit = gid >> 3;
    const int slot = unit / UNITS_PER_B;
    const int role = unit % UNITS_PER_B;
    const int bs = slot * NXCD + xcd;                               // stream batch
    const int bg = ((slot + NSLOT - 1) & (NSLOT - 1)) * NXCD + xcd; // gather batch
    if (role < NBLK_O) {
        batch_sum_obj_body(obj, bs, role, sumO);
    } else if (role < NBLK_O + GO_) {
        const int r = role - NBLK_O;
        part_stats_split_body<NO_, KO_, DIVO_>(obj, sortedO, Ks, bg,
                                               r >> 2, r & 3, splitO);
    } else if (role < NBLK_O + GO_ + NBLK_S) {
        batch_sum_smpl_body(smpl, bs, role - (NBLK_O + GO_), sumS);
    } else {
        const int r = role - (NBLK_O + GO_ + NBLK_S);
        part_stats_split_body<NS_, KS_, DIVS_>(smpl, sortedS, Ks, bg,
                                               r >> 1, r & 1, splitS);
    }
}

// ---------------------------------------------------------------------------
// Kernel D: fold split-stats, then per-batch pair masking + partial sums
// (verbatim r13/r14). Min/max fold exact -> mask bits identical.
// ---------------------------------------------------------------------------
__global__ __launch_bounds__(64) void pair_kernel(
        const float* __restrict__ splitS, const float* __restrict__ splitO,
        float* __restrict__ partial) {
#pragma clang fp contract(off)
    const int b = blockIdx.x;
    __shared__ float sS[P_][9];
    __shared__ float sO[P_][9];
    const int t = threadIdx.x;
    for (int q = t; q < 2 * P_ * 9; q += 64) {
        const int tensor = q / (P_ * 9);
        const int r = q % (P_ * 9);
        const int p = r / 9, k = r % 9;
        const float* hsrc = (tensor == 0) ? splitS : splitO;
        const int div = (tensor == 0) ? DIVS_ : DIVO_;
        float val = hsrc[(((size_t)b * P_ + p) * div + 0) * 9 + k];
        for (int h = 1; h < div; ++h) {
            const float hv = hsrc[(((size_t)b * P_ + p) * div + h) * 9 + k];
            if (k == 0 || k == 2 || k == 4)      val = fminf(val, hv);
            else if (k == 1 || k == 3 || k == 5) val = fmaxf(val, hv);
            else                                 val = val + hv;
        }
        if (tensor == 0) sS[p][k] = val; else sO[p][k] = val;
    }
    __syncthreads();

    const int ps = t >> 3;
    const int po = t & 7;

    const float* ssp = sS[po];
    const float* sop = sO[po];
    const float pcu = (ssp[0] + ssp[1]) * 0.5f;
    const float phu = (ssp[1] - ssp[0]) * 0.5f * 1.5f;
    const float pcw = (ssp[2] + ssp[3]) * 0.5f;
    const float phw = (ssp[3] - ssp[2]) * 0.5f * 1.5f;
    const float px0 = pcu - phu, px1 = pcu + phu;
    const float py0 = pcw - phw, py1 = pcw + phw;
    const float ocu = (sop[0] + sop[1]) * 0.5f;
    const float ohu = (sop[1] - sop[0]) * 0.5f * 1.5f;
    const float ocw = (sop[2] + sop[3]) * 0.5f;
    const float ohw = (sop[3] - sop[2]) * 0.5f * 1.5f;
    const float ox0 = ocu - ohu, ox1 = ocu + ohu;
    const float oy0 = ocw - ohw, oy1 = ocw + ohw;
    const bool ov = !((ox0 > px1) || (px0 > ox1) || (oy0 > py1) || (py0 > oy1));

    const float a  = sS[ps][4];
    const float bm = sS[ps][5];
    const float c  = sO[po][4];
    const float d  = sO[po][5];
    const float gap = fminf(fabsf(c - bm), fabsf(a - d));
    const float zd = ((d >= a) && (bm >= c)) ? 0.f : gap;
    const bool m = ov && (zd < ZTH_);

    const float ms0 = sS[ps][6] / (float)KS_;
    const float ms1 = sS[ps][7] / (float)KS_;
    const float ms2 = sS[ps][8] / (float)KS_;
    const float mo0 = sO[po][6] / (float)KO_;
    const float mo1 = sO[po][7] / (float)KO_;
    const float mo2 = sO[po][8] / (float)KO_;
    const float d0 = ms0 - mo0, d1 = ms1 - mo1, d2 = ms2 - mo2;
    const float pm = (d0 * d0 + d1 * d1 + d2 * d2) / 3.0f;

    float psum = m ? pm : 0.f;
    float pcnt = m ? 1.f : 0.f;
    psum = wredsum(psum);
    pcnt = wredsum(pcnt);
    if (t == 0) {
        partial[(size_t)b * 2 + 0] = psum;
        partial[(size_t)b * 2 + 1] = pcnt;
    }
}

// ---------------------------------------------------------------------------
// Kernel E: loss_inter + final reduce (verbatim round-6/8/12/13/14).
// ---------------------------------------------------------------------------
__global__ __launch_bounds__(256) void last_kernel(
        const float* __restrict__ sumS, const float* __restrict__ sumO,
        const float* __restrict__ pairPartial, float* __restrict__ out) {
    const int t = threadIdx.x;
    float d2 = 0.f;
#pragma unroll
    for (int c = 0; c < 3; ++c) {
        float ss = 0.f, so = 0.f;
#pragma unroll
        for (int k = 0; k < NBLK_S; ++k) ss += sumS[((size_t)t * NBLK_S + k) * 3 + c];
#pragma unroll
        for (int k = 0; k < NBLK_O; ++k) so += sumO[((size_t)t * NBLK_O + k) * 3 + c];
        const float ms = ss / (float)NS_;
        const float mo = so / (float)NO_;
        const float d = ms - mo;
        d2 += d * d;
    }
    float s = pairPartial[(size_t)t * 2 + 0];
    float c2 = pairPartial[(size_t)t * 2 + 1];
    __shared__ float rli[4], rs[4], rc[4];
    const float rl = wredsum(d2);
    const float ss2 = wredsum(s);
    const float cc = wredsum(c2);
    const int lane = t & 63, wv = t >> 6;
    if (lane == 0) { rli[wv] = rl; rs[wv] = ss2; rc[wv] = cc; }
    __syncthreads();
    if (t == 0) {
        const float tot = rli[0] + rli[1] + rli[2] + rli[3];
        out[0] = tot / (3.0f * (float)B_) / (float)B_;
        const float S = rs[0] + rs[1] + rs[2] + rs[3];
        const float C = rc[0] + rc[1] + rc[2] + rc[3];
        out[1] = (C > 0.f) ? (S / C) : 0.f;
    }
}

// ---------------------------------------------------------------------------
extern "C" void kernel_launch(void* const* d_in, const int* in_sizes, int n_in,
                              void* d_out, int out_size, void* d_ws, size_t ws_size,
                              hipStream_t stream) {
    const float* smpl = (const float*)d_in[0];
    const float* obj  = (const float*)d_in[1];
    const float* Ks   = (const float*)d_in[2];
    const int*   sidx = (const int*)d_in[3];
    const int*   oidx = (const int*)d_in[4];
    float* out = (float*)d_out;

    int* sortedO = (int*)d_ws;                             // 8*2048 = 16384
    int* sortedS = sortedO + (size_t)P_ * KO_;             // 8*1024 = 8192
    float* w = (float*)(sortedS + (size_t)P_ * KS_);
    float* sumO   = w;                                     // 256*16*3 = 12288
    float* sumS   = sumO + (size_t)B_ * NBLK_O * 3;        // 256*4*3  = 3072
    float* splitS = sumS + (size_t)B_ * NBLK_S * 3;        // 256*8*2*9 = 36864
    float* splitO = splitS + (size_t)B_ * P_ * DIVS_ * 9;  // 256*8*4*9 = 73728
    float* pairP  = splitO + (size_t)B_ * P_ * DIVO_ * 9;  // 512

    sort_idx_kernel<<<2 * P_, 256, 0, stream>>>(oidx, sidx, sortedO, sortedS);
    phase1_kernel<<<B_ * UNITS_PER_B, 256, 0, stream>>>(
        obj, smpl, Ks, sortedS, sortedO, sumO, sumS, splitO, splitS);
    pair_kernel<<<B_, 64, 0, stream>>>(splitS, splitO, pairP);
    last_kernel<<<1, 256, 0, stream>>>(sumS, sumO, pairP, out);
}

// Round 16
// 62.456 us; speedup vs baseline: 2.0443x; 2.0443x over previous
//
#include <hip/hip_runtime.h>
#include <math.h>

// PHOSA interaction loss, MI355X — round 16: revert to r14 (62.1 us, absmax
// 0.0), the proven optimum. r15's sorted-index experiment regressed to 128 us
// (all same-quarter gather blocks hit the same ~196 KB value range -> L2
// channel hotspotting); random-spread indices load-balance the cache.
// Final structure: one fused phase1 (stream roles: float4 obj / scalar smpl
// batch sums; gather roles: quarter/half-split dwordx4 part stats, prev-slot
// batch on same XCD) + tiny pair/last kernels. Ladder: 160.7 -> 62.1 us.
constexpr int B_   = 256;
constexpr int NS_  = 10475;
constexpr int NO_  = 65536;
constexpr int P_   = 8;
constexpr int KS_  = 1024;
constexpr int KO_  = 2048;
constexpr int NBLK_S = 4;    // stream blocks per batch, smpl
constexpr int NBLK_O = 16;   // stream blocks per batch, object (4096 verts)
constexpr int DIVO_ = 4;     // obj gather split
constexpr int DIVS_ = 2;     // smpl gather split
constexpr float EPS_ = 1e-9f;
constexpr float ZTH_ = 5.0f;

// per-batch units: 16 objsum | 32 objgather-qtr | 4 smplsum | 16 smplgather-half
constexpr int GO_ = P_ * DIVO_;                          // 32
constexpr int GS_ = P_ * DIVS_;                          // 16
constexpr int UNITS_PER_B = NBLK_O + GO_ + NBLK_S + GS_; // 68
constexpr int NXCD = 8;
constexpr int NSLOT = B_ / NXCD;                         // 32

// 16 B vector with 4 B alignment (emits global_load_dwordx4 from 12 B stride).
typedef float f32x4a4 __attribute__((ext_vector_type(4), aligned(4)));

#define DEV_INLINE __device__ __forceinline__

DEV_INLINE float wredsum(float v) {
#pragma unroll
    for (int o = 32; o; o >>= 1) v += __shfl_down(v, o);
    return v;
}
DEV_INLINE float wredmin(float v) {
#pragma unroll
    for (int o = 32; o; o >>= 1) v = fminf(v, __shfl_down(v, o));
    return v;
}
DEV_INLINE float wredmax(float v) {
#pragma unroll
    for (int o = 32; o; o >>= 1) v = fmaxf(v, __shfl_down(v, o));
    return v;
}

// ---------------------------------------------------------------------------
// Object stream role: float4-vectorized batch partial sums (verbatim r9/r14).
// Chunk = 4096 verts = 3072 float4; 256 threads x 12 float4.
// Thread t, iter j handles 4-vertex group g = j*256 + t:
//   f0=(x0,y0,z0,x1) f1=(y1,z1,x2,y2) f2=(z2,x3,y3,z3).
// ---------------------------------------------------------------------------
DEV_INLINE void batch_sum_obj_body(const float* __restrict__ v, int b, int blk,
                                   float* __restrict__ out) {
    const float4* base = reinterpret_cast<const float4*>(
        v + (size_t)b * NO_ * 3 + (size_t)blk * 4096 * 3);
    const int t = threadIdx.x;
    float4 f[12];
#pragma unroll
    for (int j = 0; j < 4; ++j) {
        const int g = j * 256 + t;
#pragma unroll
        for (int q = 0; q < 3; ++q) f[j * 3 + q] = base[g * 3 + q];
    }
    float sx = 0.f, sy = 0.f, sz = 0.f;
#pragma unroll
    for (int j = 0; j < 4; ++j) {
        const float4 f0 = f[j * 3 + 0], f1 = f[j * 3 + 1], f2 = f[j * 3 + 2];
        sx += f0.x + f0.w + f1.z + f2.y;
        sy += f0.y + f1.x + f1.w + f2.z;
        sz += f0.z + f1.y + f2.x + f2.w;
    }
    __shared__ float red[3][4];
    const float r0 = wredsum(sx), r1 = wredsum(sy), r2 = wredsum(sz);
    const int lane = t & 63, wv = t >> 6;
    if (lane == 0) { red[0][wv] = r0; red[1][wv] = r1; red[2][wv] = r2; }
    __syncthreads();
    if (t == 0) {
        float* o = out + ((size_t)b * NBLK_O + blk) * 3;
        o[0] = red[0][0] + red[0][1] + red[0][2] + red[0][3];
        o[1] = red[1][0] + red[1][1] + red[1][2] + red[1][3];
        o[2] = red[2][0] + red[2][1] + red[2][2] + red[2][3];
    }
}

// ---------------------------------------------------------------------------
// smpl stream role: scalar partial sums (verbatim round-6/8/12/13/14).
// ---------------------------------------------------------------------------
DEV_INLINE void batch_sum_smpl_body(const float* __restrict__ v, int b, int blk,
                                    float* __restrict__ out) {
    constexpr int chunk = (NS_ + NBLK_S - 1) / NBLK_S;
    const int s = blk * chunk;
    const int e = min(NS_, s + chunk);
    const float* base = v + (size_t)b * NS_ * 3;
    float sx = 0.f, sy = 0.f, sz = 0.f;
    for (int i = s + (int)threadIdx.x; i < e; i += 256) {
        const float* p = base + (size_t)i * 3;
        sx += p[0];
        sy += p[1];
        sz += p[2];
    }
    __shared__ float red[3][4];
    float r0 = wredsum(sx), r1 = wredsum(sy), r2 = wredsum(sz);
    const int lane = threadIdx.x & 63, wv = threadIdx.x >> 6;
    if (lane == 0) { red[0][wv] = r0; red[1][wv] = r1; red[2][wv] = r2; }
    __syncthreads();
    if (threadIdx.x == 0) {
        float* o = out + ((size_t)b * NBLK_S + blk) * 3;
        o[0] = red[0][0] + red[0][1] + red[0][2] + red[0][3];
        o[1] = red[1][0] + red[1][1] + red[1][2] + red[1][3];
        o[2] = red[2][0] + red[2][1] + red[2][2] + red[2][3];
    }
}

// ---------------------------------------------------------------------------
// Gather role: 1/DIV of one (batch,part) index list -> 9 split-stats
// (verbatim r13/r14). dwordx4 per vertex; global-last vertex shifted (r10).
// ---------------------------------------------------------------------------
template <int N, int K, int DIV>
DEV_INLINE void part_stats_split_body(const float* __restrict__ v,
                                      const int* __restrict__ pidx,
                                      const float* __restrict__ Ks,
                                      int b, int p, int h,
                                      float* __restrict__ out) {
    const float fx = Ks[b * 9 + 0];
    const float cx = Ks[b * 9 + 2];
    const float fy = Ks[b * 9 + 4];
    const float cy = Ks[b * 9 + 5];
    const float* base = v + (size_t)b * N * 3;
    const int* idx = pidx + (size_t)p * K + (size_t)h * (K / DIV);
    const bool lastBatch = (b == B_ - 1);

    constexpr int ITER = (K / DIV) / 256;
    int ids[ITER];
#pragma unroll
    for (int j = 0; j < ITER; ++j) ids[j] = idx[threadIdx.x + j * 256];

    float vx[ITER], vy[ITER], vz[ITER];
#pragma unroll
    for (int j = 0; j < ITER; ++j) {
        const bool shift = lastBatch && (ids[j] == N - 1);
        const float* vp = base + (size_t)ids[j] * 3 - (shift ? 1 : 0);
        const f32x4a4 f = *reinterpret_cast<const f32x4a4*>(vp);
        vx[j] = shift ? f.y : f.x;
        vy[j] = shift ? f.z : f.y;
        vz[j] = shift ? f.w : f.z;
    }

    float umin = INFINITY, umax = -INFINITY, wmin = INFINITY, wmax = -INFINITY;
    float zmin = INFINITY, zmax = -INFINITY;
    float sx = 0.f, sy = 0.f, sz = 0.f;
#pragma unroll
    for (int j = 0; j < ITER; ++j) {
        const float x = vx[j], y = vy[j], z = vz[j];
        sx += x; sy += y; sz += z;
        zmin = fminf(zmin, z); zmax = fmaxf(zmax, z);
        float u, w;
        {
#pragma clang fp contract(off)
            const float zd = z + EPS_;
            const float x_ = x / zd;
            const float y_ = (-y) / zd;
            u = fx * x_ + cx;
            w = 1.0f - (fy * y_ + cy);
            u = 2.0f * (u - 0.5f);
            w = 2.0f * (w - 0.5f);
        }
        umin = fminf(umin, u); umax = fmaxf(umax, u);
        wmin = fminf(wmin, w); wmax = fmaxf(wmax, w);
    }

    __shared__ float red[4][9];
    float r[9];
    r[0] = wredmin(umin); r[1] = wredmax(umax);
    r[2] = wredmin(wmin); r[3] = wredmax(wmax);
    r[4] = wredmin(zmin); r[5] = wredmax(zmax);
    r[6] = wredsum(sx);   r[7] = wredsum(sy); r[8] = wredsum(sz);
    const int lane = threadIdx.x & 63, wv = threadIdx.x >> 6;
    if (lane == 0) {
#pragma unroll
        for (int q = 0; q < 9; ++q) red[wv][q] = r[q];
    }
    __syncthreads();
    if (threadIdx.x == 0) {
        float* o = out + (((size_t)b * P_ + p) * DIV + h) * 9;
        o[0] = fminf(fminf(red[0][0], red[1][0]), fminf(red[2][0], red[3][0]));
        o[1] = fmaxf(fmaxf(red[0][1], red[1][1]), fmaxf(red[2][1], red[3][1]));
        o[2] = fminf(fminf(red[0][2], red[1][2]), fminf(red[2][2], red[3][2]));
        o[3] = fmaxf(fmaxf(red[0][3], red[1][3]), fmaxf(red[2][3], red[3][3]));
        o[4] = fminf(fminf(red[0][4], red[1][4]), fminf(red[2][4], red[3][4]));
        o[5] = fmaxf(fmaxf(red[0][5], red[1][5]), fmaxf(red[2][5], red[3][5]));
        o[6] = red[0][6] + red[1][6] + red[2][6] + red[3][6];
        o[7] = red[0][7] + red[1][7] + red[2][7] + red[3][7];
        o[8] = red[0][8] + red[1][8] + red[2][8] + red[3][8];
    }
}

// ---------------------------------------------------------------------------
// Phase 1: gid -> xcd = gid&7, unit = gid>>3, slot = unit/68, role = unit%68.
// Stream roles: batch slot*8+xcd. Gather roles: previous slot's batch.
// role: [0,16) objsum | [16,48) objgather-qtr (p=r>>2, h=r&3)
//     | [48,52) smplsum | [52,68) smplgather-half (p=r>>1, h=r&1).
// ---------------------------------------------------------------------------
__global__ __launch_bounds__(256) void phase1_kernel(
        const float* __restrict__ obj, const float* __restrict__ smpl,
        const float* __restrict__ Ks,
        const int* __restrict__ sidx, const int* __restrict__ oidx,
        float* __restrict__ sumO, float* __restrict__ sumS,
        float* __restrict__ splitO, float* __restrict__ splitS) {
    const int gid = blockIdx.x;
    const int xcd = gid & (NXCD - 1);
    const int unit = gid >> 3;
    const int slot = unit / UNITS_PER_B;
    const int role = unit % UNITS_PER_B;
    const int bs = slot * NXCD + xcd;                               // stream batch
    const int bg = ((slot + NSLOT - 1) & (NSLOT - 1)) * NXCD + xcd; // gather batch
    if (role < NBLK_O) {
        batch_sum_obj_body(obj, bs, role, sumO);
    } else if (role < NBLK_O + GO_) {
        const int r = role - NBLK_O;
        part_stats_split_body<NO_, KO_, DIVO_>(obj, oidx, Ks, bg,
                                               r >> 2, r & 3, splitO);
    } else if (role < NBLK_O + GO_ + NBLK_S) {
        batch_sum_smpl_body(smpl, bs, role - (NBLK_O + GO_), sumS);
    } else {
        const int r = role - (NBLK_O + GO_ + NBLK_S);
        part_stats_split_body<NS_, KS_, DIVS_>(smpl, sidx, Ks, bg,
                                               r >> 1, r & 1, splitS);
    }
}

// ---------------------------------------------------------------------------
// Kernel D: fold split-stats, then per-batch pair masking + partial sums
// (verbatim r13/r14). Min/max fold exact -> mask bits identical.
// ---------------------------------------------------------------------------
__global__ __launch_bounds__(64) void pair_kernel(
        const float* __restrict__ splitS, const float* __restrict__ splitO,
        float* __restrict__ partial) {
#pragma clang fp contract(off)
    const int b = blockIdx.x;
    __shared__ float sS[P_][9];
    __shared__ float sO[P_][9];
    const int t = threadIdx.x;
    for (int q = t; q < 2 * P_ * 9; q += 64) {
        const int tensor = q / (P_ * 9);
        const int r = q % (P_ * 9);
        const int p = r / 9, k = r % 9;
        const float* hsrc = (tensor == 0) ? splitS : splitO;
        const int div = (tensor == 0) ? DIVS_ : DIVO_;
        float val = hsrc[(((size_t)b * P_ + p) * div + 0) * 9 + k];
        for (int h = 1; h < div; ++h) {
            const float hv = hsrc[(((size_t)b * P_ + p) * div + h) * 9 + k];
            if (k == 0 || k == 2 || k == 4)      val = fminf(val, hv);
            else if (k == 1 || k == 3 || k == 5) val = fmaxf(val, hv);
            else                                 val = val + hv;
        }
        if (tensor == 0) sS[p][k] = val; else sO[p][k] = val;
    }
    __syncthreads();

    const int ps = t >> 3;
    const int po = t & 7;

    const float* ssp = sS[po];
    const float* sop = sO[po];
    const float pcu = (ssp[0] + ssp[1]) * 0.5f;
    const float phu = (ssp[1] - ssp[0]) * 0.5f * 1.5f;
    const float pcw = (ssp[2] + ssp[3]) * 0.5f;
    const float phw = (ssp[3] - ssp[2]) * 0.5f * 1.5f;
    const float px0 = pcu - phu, px1 = pcu + phu;
    const float py0 = pcw - phw, py1 = pcw + phw;
    const float ocu = (sop[0] + sop[1]) * 0.5f;
    const float ohu = (sop[1] - sop[0]) * 0.5f * 1.5f;
    const float ocw = (sop[2] + sop[3]) * 0.5f;
    const float ohw = (sop[3] - sop[2]) * 0.5f * 1.5f;
    const float ox0 = ocu - ohu, ox1 = ocu + ohu;
    const float oy0 = ocw - ohw, oy1 = ocw + ohw;
    const bool ov = !((ox0 > px1) || (px0 > ox1) || (oy0 > py1) || (py0 > oy1));

    const float a  = sS[ps][4];
    const float bm = sS[ps][5];
    const float c  = sO[po][4];
    const float d  = sO[po][5];
    const float gap = fminf(fabsf(c - bm), fabsf(a - d));
    const float zd = ((d >= a) && (bm >= c)) ? 0.f : gap;
    const bool m = ov && (zd < ZTH_);

    const float ms0 = sS[ps][6] / (float)KS_;
    const float ms1 = sS[ps][7] / (float)KS_;
    const float ms2 = sS[ps][8] / (float)KS_;
    const float mo0 = sO[po][6] / (float)KO_;
    const float mo1 = sO[po][7] / (float)KO_;
    const float mo2 = sO[po][8] / (float)KO_;
    const float d0 = ms0 - mo0, d1 = ms1 - mo1, d2 = ms2 - mo2;
    const float pm = (d0 * d0 + d1 * d1 + d2 * d2) / 3.0f;

    float psum = m ? pm : 0.f;
    float pcnt = m ? 1.f : 0.f;
    psum = wredsum(psum);
    pcnt = wredsum(pcnt);
    if (t == 0) {
        partial[(size_t)b * 2 + 0] = psum;
        partial[(size_t)b * 2 + 1] = pcnt;
    }
}

// ---------------------------------------------------------------------------
// Kernel E: loss_inter + final reduce (verbatim round-6/8/12/13/14).
// ---------------------------------------------------------------------------
__global__ __launch_bounds__(256) void last_kernel(
        const float* __restrict__ sumS, const float* __restrict__ sumO,
        const float* __restrict__ pairPartial, float* __restrict__ out) {
    const int t = threadIdx.x;
    float d2 = 0.f;
#pragma unroll
    for (int c = 0; c < 3; ++c) {
        float ss = 0.f, so = 0.f;
#pragma unroll
        for (int k = 0; k < NBLK_S; ++k) ss += sumS[((size_t)t * NBLK_S + k) * 3 + c];
#pragma unroll
        for (int k = 0; k < NBLK_O; ++k) so += sumO[((size_t)t * NBLK_O + k) * 3 + c];
        const float ms = ss / (float)NS_;
        const float mo = so / (float)NO_;
        const float d = ms - mo;
        d2 += d * d;
    }
    float s = pairPartial[(size_t)t * 2 + 0];
    float c2 = pairPartial[(size_t)t * 2 + 1];
    __shared__ float rli[4], rs[4], rc[4];
    const float rl = wredsum(d2);
    const float ss2 = wredsum(s);
    const float cc = wredsum(c2);
    const int lane = t & 63, wv = t >> 6;
    if (lane == 0) { rli[wv] = rl; rs[wv] = ss2; rc[wv] = cc; }
    __syncthreads();
    if (t == 0) {
        const float tot = rli[0] + rli[1] + rli[2] + rli[3];
        out[0] = tot / (3.0f * (float)B_) / (float)B_;
        const float S = rs[0] + rs[1] + rs[2] + rs[3];
        const float C = rc[0] + rc[1] + rc[2] + rc[3];
        out[1] = (C > 0.f) ? (S / C) : 0.f;
    }
}

// ---------------------------------------------------------------------------
extern "C" void kernel_launch(void* const* d_in, const int* in_sizes, int n_in,
                              void* d_out, int out_size, void* d_ws, size_t ws_size,
                              hipStream_t stream) {
    const float* smpl = (const float*)d_in[0];
    const float* obj  = (const float*)d_in[1];
    const float* Ks   = (const float*)d_in[2];
    const int*   sidx = (const int*)d_in[3];
    const int*   oidx = (const int*)d_in[4];
    float* out = (float*)d_out;

    float* w = (float*)d_ws;
    float* sumO   = w;                                     // 256*16*3 = 12288
    float* sumS   = sumO + (size_t)B_ * NBLK_O * 3;        // 256*4*3  = 3072
    float* splitS = sumS + (size_t)B_ * NBLK_S * 3;        // 256*8*2*9 = 36864
    float* splitO = splitS + (size_t)B_ * P_ * DIVS_ * 9;  // 256*8*4*9 = 73728
    float* pairP  = splitO + (size_t)B_ * P_ * DIVO_ * 9;  // 512

    phase1_kernel<<<B_ * UNITS_PER_B, 256, 0, stream>>>(
        obj, smpl, Ks, sidx, oidx, sumO, sumS, splitO, splitS);
    pair_kernel<<<B_, 64, 0, stream>>>(splitS, splitO, pairP);
    last_kernel<<<1, 256, 0, stream>>>(sumS, sumO, pairP, out);
}